// Round 10
// baseline (230.330 us; speedup 1.0000x reference)
//
#include <hip/hip_runtime.h>

// VQ-VAE vector quantizer, round 10: wave-count discriminator at constant per-CU work.
// R4/R8/R9 (2 waves/SIMD) all ~96-103us with ~89% idle issue slots; per-SIMD issue sum is
// only ~11us -> latency exposure at 2 waves/SIMD is the surviving theory. This round keeps
// per-CU MFMA count and B-traffic IDENTICAL to R9 but splits it across 3-4x more waves:
// NPB=16 (one 16x16 tile/block), 4096 blocks, each wave scans a disjoint 256-code quarter
// (codes [256w,256w+256)); launch_bounds(256,6) caps VGPR at ~84 (no spills - WRITE canary).
// Cross-wave exact top-2 merge via LDS. Loss via per-block partials + 1-block reduce kernel
// (no same-address atomics). Near-ties (gap<1e-3, err~1e-4) rescanned exactly in fp32.
// out (fp32 concat): [ loss(1) | quantized NCHW (4194304) | indices as float (65536) ]

#define DIMS   64
#define HW     4096
#define NPTS   65536
#define NCODES 1024
#define NPB    16
#define NBLK   (NPTS / NPB)        // 4096
#define QOFF   1
#define IOFF   (1 + NPTS * DIMS)
#define EPSGAP 1.0e-3f

typedef unsigned int uint;
typedef unsigned short ushort;
typedef unsigned long long ull;
typedef __attribute__((ext_vector_type(8))) short short8;
typedef __attribute__((ext_vector_type(4))) float f32x4;

__device__ __forceinline__ ushort bf16_rne(float f) {
    uint u = __float_as_uint(f);
    uint r = u + 0x7FFFu + ((u >> 16) & 1u);
    return (ushort)(r >> 16);
}
__device__ __forceinline__ float bf16f(ushort h) { return __uint_as_float(((uint)h) << 16); }

// ---- prep: emb fp32 -> {Eh, El bf16 [1024][64]}, hsq = 0.5||e||^2
__global__ void vq_prep(const float* __restrict__ emb, ushort* __restrict__ Eh,
                        ushort* __restrict__ El, float* __restrict__ hsq)
{
    const int t = blockIdx.x * 256 + threadIdx.x;      // 0..16383, one float4 each
    float4 v = ((const float4*)emb)[t];
    ushort h0 = bf16_rne(v.x), h1 = bf16_rne(v.y), h2 = bf16_rne(v.z), h3 = bf16_rne(v.w);
    ushort l0 = bf16_rne(v.x - bf16f(h0)), l1 = bf16_rne(v.y - bf16f(h1));
    ushort l2 = bf16_rne(v.z - bf16f(h2)), l3 = bf16_rne(v.w - bf16f(h3));
    uint2 hp, lp;
    hp.x = (uint)h0 | ((uint)h1 << 16); hp.y = (uint)h2 | ((uint)h3 << 16);
    lp.x = (uint)l0 | ((uint)l1 << 16); lp.y = (uint)l2 | ((uint)l3 << 16);
    *(uint2*)(Eh + (size_t)t * 4) = hp;
    *(uint2*)(El + (size_t)t * 4) = lp;
    if (t < NCODES) {
        const float4* r = (const float4*)(emb + (size_t)t * DIMS);
        float s = 0.f;
        #pragma unroll
        for (int i = 0; i < 16; ++i) {
            float4 e = r[i];
            s = fmaf(e.x, e.x, s); s = fmaf(e.y, e.y, s);
            s = fmaf(e.z, e.z, s); s = fmaf(e.w, e.w, s);
        }
        hsq[t] = 0.5f * s;
    }
}

__launch_bounds__(256, 6)
__global__ void vq_main(const float* __restrict__ in, const float* __restrict__ emb,
                        const ushort* __restrict__ Ehw, const ushort* __restrict__ Elw,
                        const float* __restrict__ hsqw, float* __restrict__ out,
                        float* __restrict__ lossp)
{
    __shared__ float cv1[4][16];                       // per-wave candidates
    __shared__ float cv2[4][16];
    __shared__ int   ci1[4][16];
    __shared__ float sv1[16], sv2[16];
    __shared__ int   si1[16];
    __shared__ ull   msk;
    __shared__ int   lst[1 + 16];
    __shared__ float lred[4];

    const int tid = threadIdx.x;
    const int lane = tid & 63, w = tid >> 6;
    const int m = lane & 15, quad = lane >> 4;
    const int n0 = blockIdx.x * NPB;
    const int b = n0 >> 12, off = n0 & 4095;           // 16 | 4096: never crosses a batch
    const float* xbase = in + (size_t)b * (DIMS * HW) + off;

    // ---- A fragments: the block's 16 points (every wave loads the same tile; L1-shared).
    //      layout (verified): A[row=m][k = ks*32 + quad*8 + j]
    short8 Ah[2], Al[2];
    #pragma unroll
    for (int ks = 0; ks < 2; ++ks) {
        union { ushort u[8]; short8 v; } th, tl;
        #pragma unroll
        for (int j = 0; j < 8; ++j) {
            float x = xbase[(ks * 32 + quad * 8 + j) * HW + m];
            ushort hh = bf16_rne(x);
            th.u[j] = hh;
            tl.u[j] = bf16_rne(x - bf16f(hh));
        }
        Ah[ks] = th.v; Al[ks] = tl.v;
    }

    float v1s[4], v2s[4]; int i1s[4];
    #pragma unroll
    for (int r = 0; r < 4; ++r) { v1s[r] = 1e30f; v2s[r] = 1e30f; i1s[r] = 0; }

    // ---- K-loop: this wave's disjoint 256-code quarter, 16 groups of 16 codes.
    //      3 independent 2-deep MFMA chains (hh, hl, lh) per group.
    const int kw = w * 256;
    for (int g = 0; g < 16; ++g) {
        const int ca = kw + g * 16 + m;                // this lane's code id
        const ushort* eb = Ehw + (size_t)ca * 64 + quad * 8;
        const ushort* lb = Elw + (size_t)ca * 64 + quad * 8;
        short8 Bh0 = *(const short8*)(eb);
        short8 Bh1 = *(const short8*)(eb + 32);
        short8 Bl0 = *(const short8*)(lb);
        short8 Bl1 = *(const short8*)(lb + 32);
        const float ha = hsqw[ca];

        const f32x4 z = {0.f, 0.f, 0.f, 0.f};
        f32x4 chh, chl, clh;
        chh = __builtin_amdgcn_mfma_f32_16x16x32_bf16(Ah[0], Bh0, z, 0, 0, 0);
        chl = __builtin_amdgcn_mfma_f32_16x16x32_bf16(Ah[0], Bl0, z, 0, 0, 0);
        clh = __builtin_amdgcn_mfma_f32_16x16x32_bf16(Al[0], Bh0, z, 0, 0, 0);
        chh = __builtin_amdgcn_mfma_f32_16x16x32_bf16(Ah[1], Bh1, chh, 0, 0, 0);
        chl = __builtin_amdgcn_mfma_f32_16x16x32_bf16(Ah[1], Bl1, chl, 0, 0, 0);
        clh = __builtin_amdgcn_mfma_f32_16x16x32_bf16(Al[1], Bh1, clh, 0, 0, 0);

        #pragma unroll
        for (int r = 0; r < 4; ++r) {                  // point row = quad*4 + r
            float d = ha - (chh[r] + (chl[r] + clh[r]));
            v2s[r] = fminf(v2s[r], fmaxf(d, v1s[r]));  // exact streaming 2nd-min
            bool c2 = d < v1s[r];                      // strict: ascending g keeps lowest idx
            i1s[r] = c2 ? ca : i1s[r];
            v1s[r] = fminf(d, v1s[r]);
        }
    }

    // ---- merge across the 16 code-lanes within the wave
    #pragma unroll
    for (int st = 1; st < 16; st <<= 1) {
        #pragma unroll
        for (int r = 0; r < 4; ++r) {
            float ov1 = __shfl_xor(v1s[r], st);
            float ov2 = __shfl_xor(v2s[r], st);
            int   oi1 = __shfl_xor(i1s[r], st);
            v2s[r] = fminf(fminf(v2s[r], ov2), fmaxf(v1s[r], ov1));
            bool c = (ov1 < v1s[r]) || (ov1 == v1s[r] && oi1 < i1s[r]);
            if (c) i1s[r] = oi1;
            v1s[r] = fminf(v1s[r], ov1);
        }
    }
    if (m == 0) {                                      // lanes 0,16,32,48 -> 4 rows each
        #pragma unroll
        for (int r = 0; r < 4; ++r) {
            const int p = quad * 4 + r;
            cv1[w][p] = v1s[r]; ci1[w][p] = i1s[r]; cv2[w][p] = v2s[r];
        }
    }
    __syncthreads();

    // ---- merge the 4 wave-candidates per point (ascending wave = ascending code range)
    if (tid < NPB) {
        const int p = tid;
        float bv1 = 1e30f, bv2 = 1e30f; int bi = 0;
        #pragma unroll
        for (int ww = 0; ww < 4; ++ww) {
            float a1 = cv1[ww][p], a2 = cv2[ww][p];
            int   ai = ci1[ww][p];
            bv2 = fminf(fminf(bv2, a2), fmaxf(bv1, a1));
            if (a1 < bv1) { bv1 = a1; bi = ai; }       // strict: earlier wave wins ties
        }
        sv1[p] = bv1; sv2[p] = bv2; si1[p] = bi;
    }
    // flag near-ties via wave-0 ballot (tid<16 all live in wave 0)
    {
        bool f = (tid < NPB) && ((sv2[tid] - sv1[tid]) < EPSGAP);
        ull bm = __ballot(f);
        if (tid == 0) msk = bm;
    }
    __syncthreads();
    if (tid == 0) {
        int c = 0;
        ull m0 = msk;
        while (m0) { lst[1 + c++] = __ffsll(m0) - 1; m0 &= m0 - 1; }
        lst[0] = c;
    }
    __syncthreads();

    // ---- exact fp32 rescan, one wave per flagged point (rare: gap < 1e-3)
    const int cnt = lst[0];
    const float4* e4 = (const float4*)emb;
    for (int it = w; it < cnt; it += 4) {
        const int p = lst[1 + it];
        float xv = xbase[lane * HW + p];               // lane d holds x_d (exact fp32)
        float bv = 1e30f; int bk = 0;
        #pragma unroll
        for (int half = 0; half < 2; ++half) {
            float dacc[8];
            #pragma unroll
            for (int j = 0; j < 8; ++j) dacc[j] = 0.f;
            for (int d4 = 0; d4 < 16; ++d4) {
                float x0 = __shfl(xv, d4 * 4 + 0), x1 = __shfl(xv, d4 * 4 + 1);
                float x2 = __shfl(xv, d4 * 4 + 2), x3 = __shfl(xv, d4 * 4 + 3);
                #pragma unroll
                for (int j = 0; j < 8; ++j) {
                    const int k = lane + 64 * (half * 8 + j);
                    float4 e = e4[k * 16 + d4];
                    dacc[j] = fmaf(x0, e.x, dacc[j]); dacc[j] = fmaf(x1, e.y, dacc[j]);
                    dacc[j] = fmaf(x2, e.z, dacc[j]); dacc[j] = fmaf(x3, e.w, dacc[j]);
                }
            }
            #pragma unroll
            for (int j = 0; j < 8; ++j) {              // ascending k per lane: first-min kept
                const int k = lane + 64 * (half * 8 + j);
                float v = hsqw[k] - dacc[j];
                if (v < bv) { bv = v; bk = k; }
            }
        }
        #pragma unroll
        for (int st = 32; st; st >>= 1) {              // 64-wide (v, k) argmin, k tie-break
            float ov = __shfl_xor(bv, st);
            int   ok = __shfl_xor(bk, st);
            if (ov < bv || (ov == bv && ok < bk)) { bv = ov; bk = ok; }
        }
        if (lane == 0) si1[p] = bk;
    }
    __syncthreads();

    // ---- final: indices, quantized gather-write, per-block loss partial
    {
        const int p = tid & 15, dg = tid >> 4;         // dims dg*4 .. dg*4+3
        const int bi = si1[p];
        if (dg == 0) out[IOFF + n0 + p] = (float)bi;
        const float* e = emb + (size_t)bi * DIMS;
        const float* xp = xbase + p;
        float* oq = out + QOFF + (size_t)b * (DIMS * HW) + off + p;
        float ls = 0.f;
        #pragma unroll
        for (int d0 = 0; d0 < 4; ++d0) {
            const int d = dg * 4 + d0;
            float ev = e[d];
            float xv = xp[d * HW];
            float df = ev - xv;
            ls = fmaf(df, df, ls);
            oq[d * HW] = ev;                           // coalesced across point-threads
        }
        #pragma unroll
        for (int st = 32; st; st >>= 1) ls += __shfl_down(ls, st);
        if (lane == 0) lred[w] = ls;
    }
    __syncthreads();
    if (tid == 0) lossp[blockIdx.x] = lred[0] + lred[1] + lred[2] + lred[3];
}

// ---- final loss reduce: 4096 partials -> out[0] (plain store, no atomics)
__global__ void vq_loss(const float* __restrict__ lossp, float* __restrict__ out)
{
    __shared__ float lr[4];
    const int tid = threadIdx.x, lane = tid & 63, w = tid >> 6;
    float s = 0.f;
    #pragma unroll
    for (int i = 0; i < 16; ++i) s += lossp[tid + 256 * i];
    #pragma unroll
    for (int st = 32; st; st >>= 1) s += __shfl_down(s, st);
    if (lane == 0) lr[w] = s;
    __syncthreads();
    if (tid == 0)
        out[0] = (lr[0] + lr[1] + lr[2] + lr[3]) * (0.25f / (float)(NPTS * DIMS));
}

extern "C" void kernel_launch(void* const* d_in, const int* in_sizes, int n_in,
                              void* d_out, int out_size, void* d_ws, size_t ws_size,
                              hipStream_t stream) {
    const float* in  = (const float*)d_in[0];
    const float* emb = (const float*)d_in[1];
    float* out = (float*)d_out;
    ushort* Eh   = (ushort*)d_ws;                      // 131072 B
    ushort* El   = (ushort*)((char*)d_ws + 131072);    // 131072 B
    float*  hsq  = (float*)((char*)d_ws + 262144);     // 4096 B
    float*  lossp = (float*)((char*)d_ws + 266240);    // 16384 B
    (void)in_sizes; (void)n_in; (void)out_size; (void)ws_size;

    vq_prep<<<64, 256, 0, stream>>>(emb, Eh, El, hsq);
    vq_main<<<NBLK, 256, 0, stream>>>(in, emb, Eh, El, hsq, out, lossp);
    vq_loss<<<1, 256, 0, stream>>>(lossp, out);
}